// Round 21
// baseline (106.174 us; speedup 1.0000x reference)
//
#include <hip/hip_runtime.h>
#include <hip/hip_bf16.h>
#include <stdint.h>

#define HIDDEN 1024
#define NHEADS 16
#define DHEAD  64
#define BATCH  2
#define SEQ    2048
#define MROWS  (BATCH*SEQ)   // 4096
#define QKVC   (3*HIDDEN)    // 3072

typedef unsigned short u16;
typedef unsigned int   u32;
typedef __bf16 bf16x8 __attribute__((ext_vector_type(8)));
typedef __bf16 bf16x2 __attribute__((ext_vector_type(2)));
typedef float  f32x4  __attribute__((ext_vector_type(4)));
typedef float  f32x16 __attribute__((ext_vector_type(16)));
typedef short  s16x4  __attribute__((ext_vector_type(4)));
typedef u16    u16x8  __attribute__((ext_vector_type(8)));
typedef u32    u32x2  __attribute__((ext_vector_type(2)));

typedef const __attribute__((address_space(1))) void gvoid_t;
typedef       __attribute__((address_space(3))) void lvoid_t;

__device__ __forceinline__ gvoid_t* to_glob(const void* p){
  return (gvoid_t*)(uintptr_t)p;
}
__device__ __forceinline__ lvoid_t* to_lds(void* p){
  return (lvoid_t*)(uintptr_t)p;
}
__device__ __forceinline__ u32 lds_off(const void* p){
  return (u32)(uintptr_t)p;
}

// native f32->bf16 (hardware RNE cvt on gfx950)
__device__ __forceinline__ u16 f2bf(float x){
  __bf16 h = (__bf16)x;
  return __builtin_bit_cast(u16, h);
}
// packed f32x2 -> bf16x2 word (compiler emits v_cvt_pk_bf16_f32)
__device__ __forceinline__ u32 pk2(float a, float b){
  bf16x2 t = { (__bf16)a, (__bf16)b };
  return __builtin_bit_cast(u32, t);
}

#define MFMA32(a, b, c) __builtin_amdgcn_mfma_f32_32x32x16_bf16(a, b, c, 0, 0, 0)

// ---------------- fp32 -> bf16 conversion, weights only (enc fused into gemm1) ----
#define CVT_N1  786432   // attn_w   (3M f32 / 4)
#define CVT_N2  262144   // out_w    (1M f32 / 4)
__global__ __launch_bounds__(256) void k_cvt2(const float* __restrict__ wa,
                                              const float* __restrict__ wo,
                                              u16* __restrict__ wab,
                                              u16* __restrict__ wob){
  int i = blockIdx.x * 256 + threadIdx.x;
  const float* src; u16* dst;
  if (i < CVT_N1){ src = wa; dst = wab; }
  else if (i < CVT_N1 + CVT_N2){ i -= CVT_N1; src = wo; dst = wob; }
  else return;
  const float4 v = reinterpret_cast<const float4*>(src)[i];
  ushort4 o;
  o.x = f2bf(v.x); o.y = f2bf(v.y); o.z = f2bf(v.z); o.w = f2bf(v.w);
  reinterpret_cast<ushort4*>(dst)[i] = o;
}

// ---------------- bf16 GEMM, C = A * B^T + bias (R20-verified: T2 swizzle) ----------------
template<int NC, bool BF16OUT>
__global__ __launch_bounds__(256) void k_gemm(const u16* __restrict__ A,
                                              const u16* __restrict__ B,
                                              const float* __restrict__ bias,
                                              void* __restrict__ C){
  constexpr int K = HIDDEN;
  __shared__ u16 As[2][128*32];
  __shared__ u16 Bs[2][128*32];
  const int m0 = blockIdx.x * 128;
  const int n0 = blockIdx.y * 128;
  const int tid = threadIdx.x;
  const int w = tid >> 6, l = tid & 63;
  const int wr = w >> 1, wc = w & 1;

  const f32x4 fz = {0.f, 0.f, 0.f, 0.f};
  f32x4 acc[4][4];
  #pragma unroll
  for (int i = 0; i < 4; ++i)
    #pragma unroll
    for (int j = 0; j < 4; ++j) acc[i][j] = fz;

  const int sc = (tid & 3) ^ (((tid >> 2) >> 1) & 3);
  const u16* ap = A + (size_t)(m0 + (tid >> 2)) * K + sc * 8;
  const u16* bp = B + (size_t)(n0 + (tid >> 2)) * K + sc * 8;

  auto stage = [&](int k0, int buf){
    __builtin_amdgcn_global_load_lds(to_glob(ap + k0),        to_lds(&As[buf][w*512]),        16, 0, 0);
    __builtin_amdgcn_global_load_lds(to_glob(ap + 64*K + k0), to_lds(&As[buf][2048 + w*512]), 16, 0, 0);
    __builtin_amdgcn_global_load_lds(to_glob(bp + k0),        to_lds(&Bs[buf][w*512]),        16, 0, 0);
    __builtin_amdgcn_global_load_lds(to_glob(bp + 64*K + k0), to_lds(&Bs[buf][2048 + w*512]), 16, 0, 0);
  };

  stage(0, 0);
  __syncthreads();

  const int chunkSel = ((l >> 4) ^ ((l >> 1) & 3)) * 8;   // swizzled read chunk

  for (int k0 = 0; k0 < K; k0 += 32){
    const int cur = (k0 >> 5) & 1;
    if (k0 + 32 < K) stage(k0 + 32, cur ^ 1);

    bf16x8 af[4], bfr[4];
    #pragma unroll
    for (int mf = 0; mf < 4; ++mf)
      af[mf]  = *(const bf16x8*)&As[cur][(wr*64 + mf*16 + (l & 15))*32 + chunkSel];
    #pragma unroll
    for (int nf = 0; nf < 4; ++nf)
      bfr[nf] = *(const bf16x8*)&Bs[cur][(wc*64 + nf*16 + (l & 15))*32 + chunkSel];
    #pragma unroll
    for (int mf = 0; mf < 4; ++mf)
      #pragma unroll
      for (int nf = 0; nf < 4; ++nf)
        acc[mf][nf] = __builtin_amdgcn_mfma_f32_16x16x32_bf16(af[mf], bfr[nf], acc[mf][nf], 0, 0, 0);

    __syncthreads();
  }

  #pragma unroll
  for (int nf = 0; nf < 4; ++nf){
    const int col = n0 + wc*64 + nf*16 + (l & 15);
    const float bv = bias[col];
    #pragma unroll
    for (int mf = 0; mf < 4; ++mf){
      #pragma unroll
      for (int r = 0; r < 4; ++r){
        const int row = m0 + wr*64 + mf*16 + (l >> 4)*4 + r;
        const float v = acc[mf][nf][r] + bv;
        if constexpr (BF16OUT) ((u16*)C)[(size_t)row * NC + col] = f2bf(v);
        else                   ((float*)C)[(size_t)row * NC + col] = v;
      }
    }
  }
}

// ---------------- gemm1 variant: A is fp32 (enc), converted in-kernel ----------------
// R21: fuses the enc leg of the cvt pass into A-staging. A-path: 4 fp32
// global_load_dwordx4 issued at stage-time (T14 load-early), hardware cvt_pk,
// 2 ds_write_b128 placed AFTER compute (write-late) into the SAME LDS slots
// the DMA wrote (dest = &As[buf][w*512 + l*8] etc). WAR/visibility via the
// existing full-drain __syncthreads (no new sync). B-path/compute/epilogue
// byte-identical to k_gemm. Saves ~24MB of cvt traffic (~4.8us).
__global__ __launch_bounds__(256) void k_gemmA32(const float* __restrict__ A,
                                                 const u16* __restrict__ B,
                                                 const float* __restrict__ bias,
                                                 u16* __restrict__ C){
  constexpr int K = HIDDEN;
  constexpr int NC = QKVC;
  __shared__ u16 As[2][128*32];
  __shared__ u16 Bs[2][128*32];
  const int m0 = blockIdx.x * 128;
  const int n0 = blockIdx.y * 128;
  const int tid = threadIdx.x;
  const int w = tid >> 6, l = tid & 63;
  const int wr = w >> 1, wc = w & 1;

  const f32x4 fz = {0.f, 0.f, 0.f, 0.f};
  f32x4 acc[4][4];
  #pragma unroll
  for (int i = 0; i < 4; ++i)
    #pragma unroll
    for (int j = 0; j < 4; ++j) acc[i][j] = fz;

  const int sc = (tid & 3) ^ (((tid >> 2) >> 1) & 3);
  const float* apf = A + (size_t)(m0 + (tid >> 2)) * K + sc * 8;   // fp32 source
  const u16*   bp  = B + (size_t)(n0 + (tid >> 2)) * K + sc * 8;

  float4 av[4];    // staged A fp32 (rows tid>>2 and 64+tid>>2, 8 floats each)

  auto loadA = [&](int k0){
    const float* p0 = apf + k0;
    const float* p1 = apf + 64*K + k0;
    av[0] = *(const float4*)(p0);
    av[1] = *(const float4*)(p0 + 4);
    av[2] = *(const float4*)(p1);
    av[3] = *(const float4*)(p1 + 4);
  };
  auto writeA = [&](int buf){
    union { u32 wd[4]; u16x8 v; } c0, c1;
    c0.wd[0] = pk2(av[0].x, av[0].y); c0.wd[1] = pk2(av[0].z, av[0].w);
    c0.wd[2] = pk2(av[1].x, av[1].y); c0.wd[3] = pk2(av[1].z, av[1].w);
    c1.wd[0] = pk2(av[2].x, av[2].y); c1.wd[1] = pk2(av[2].z, av[2].w);
    c1.wd[2] = pk2(av[3].x, av[3].y); c1.wd[3] = pk2(av[3].z, av[3].w);
    *(u16x8*)&As[buf][w*512 + l*8]        = c0.v;
    *(u16x8*)&As[buf][2048 + w*512 + l*8] = c1.v;
  };
  auto stageB = [&](int k0, int buf){
    __builtin_amdgcn_global_load_lds(to_glob(bp + k0),        to_lds(&Bs[buf][w*512]),        16, 0, 0);
    __builtin_amdgcn_global_load_lds(to_glob(bp + 64*K + k0), to_lds(&Bs[buf][2048 + w*512]), 16, 0, 0);
  };

  // prologue: A(0) via regs (compiler waits), B(0) via DMA
  loadA(0);
  writeA(0);
  stageB(0, 0);
  __syncthreads();

  const int chunkSel = ((l >> 4) ^ ((l >> 1) & 3)) * 8;   // swizzled read chunk

  for (int k0 = 0; k0 < K; k0 += 32){
    const int cur = (k0 >> 5) & 1;
    const bool pf = (k0 + 32 < K);
    if (pf){ loadA(k0 + 32); stageB(k0 + 32, cur ^ 1); }   // loads issue early

    bf16x8 af[4], bfr[4];
    #pragma unroll
    for (int mf = 0; mf < 4; ++mf)
      af[mf]  = *(const bf16x8*)&As[cur][(wr*64 + mf*16 + (l & 15))*32 + chunkSel];
    #pragma unroll
    for (int nf = 0; nf < 4; ++nf)
      bfr[nf] = *(const bf16x8*)&Bs[cur][(wc*64 + nf*16 + (l & 15))*32 + chunkSel];
    #pragma unroll
    for (int mf = 0; mf < 4; ++mf)
      #pragma unroll
      for (int nf = 0; nf < 4; ++nf)
        acc[mf][nf] = __builtin_amdgcn_mfma_f32_16x16x32_bf16(af[mf], bfr[nf], acc[mf][nf], 0, 0, 0);

    if (pf) writeA(cur ^ 1);   // fp32 load latency hidden under the MFMAs above
    __syncthreads();           // drains B DMA + A ds_writes; protects buf reuse

  }

  #pragma unroll
  for (int nf = 0; nf < 4; ++nf){
    const int col = n0 + wc*64 + nf*16 + (l & 15);
    const float bv = bias[col];
    #pragma unroll
    for (int mf = 0; mf < 4; ++mf){
      #pragma unroll
      for (int r = 0; r < 4; ++r){
        const int row = m0 + wr*64 + mf*16 + (l >> 4)*4 + r;
        C[(size_t)row * NC + col] = f2bf(acc[mf][nf][r] + bv);
      }
    }
  }
}

// ---------------- causal flash attention: counted-vmcnt, K 3-buf / V 2-buf ----
// EXACT R12/R19/R20 (verified 45.8-46.6us / absmax 0.0049).
// Known dead ends (R13-R18): sync-scheme changes plateau-neutral; tail
// equalization spills; permlane32_swap(x,x) self-swap BANNED; 32KB/5-block
// variant (R13) failed unexplained — do not re-roll without root cause.
__global__ __launch_bounds__(256, 4) void k_attn(const u16* __restrict__ qkv,
                                                 u16* __restrict__ aout){
  __shared__ u16 smem[20480];   // 40 KiB: half hr at [hr*10240]: K 3x2048 | V 2x2048 (u16)

  const int bh = blockIdx.x;
  const int b  = bh >> 4;
  const int h  = bh & 15;
  const int qt = 31 - blockIdx.y;          // LPT: longest blocks first
  const int tid = threadIdx.x;
  const int l  = tid & 63;
  const int w  = tid >> 6;
  const int hr = w >> 1;                   // k-half (0 or 1)
  const int wr = w & 1;                    // q-row half within tile
  const int t128 = tid & 127;
  const int lw = t128 >> 6;                // wave-within-half
  const int U  = qt + 1;                   // 32-k units per half (uniform)
  const int kb = hr ? U : 0;               // my first unit
  const int kmax = kb + U - 1;             // clamp target for tail prefetch
  const int q0 = qt*64 + wr*32;            // this wave's 32 q-rows
  const size_t base = (size_t)b * SEQ * QKVC + (size_t)h * 192;
  const float CEXP = 0.18033688011112042f; // 0.125 * log2(e)

  u16* const Kreg = smem + hr*10240;          // + cb*2048 (u16), cb in {0,1,2}
  u16* const Vreg = smem + hr*10240 + 6144;   // + vb*2048 (u16), vb in {0,1}

  // ---- per-lane staging source bases (XOR pre-swizzled K; inverse-subtile V)
  const int cgK = (t128 & 7) ^ ((t128 >> 3) & 7);
  const u16* const baseK = qkv + base + (size_t)(t128 >> 3) * QKVC + 64 + cgK * 8;
  const int vk = ((t128 >> 5) << 2) | ((t128 >> 1) & 3);
  const int vd = (((t128 >> 3) & 3) << 4) | ((t128 & 1) << 3);
  const u16* const baseV = qkv + base + (size_t)vk * QKVC + 128 + vd;

  auto stageK = [&](int u, int cb){   // 2 vmem instrs per wave
    const u16* pk = baseK + (size_t)u * 32 * QKVC;
    #pragma unroll
    for (int t = 0; t < 2; ++t)
      __builtin_amdgcn_global_load_lds(to_glob(pk + t*16*QKVC),
                                       to_lds(&Kreg[cb*2048 + t*1024 + lw*512]), 16, 0, 0);
  };
  auto stageV = [&](int u, int vb){   // 2 vmem instrs per wave
    const u16* pv = baseV + (size_t)u * 32 * QKVC;
    #pragma unroll
    for (int t = 0; t < 2; ++t)
      __builtin_amdgcn_global_load_lds(to_glob(pv + t*16*QKVC),
                                       to_lds(&Vreg[vb*2048 + t*1024 + lw*512]), 16, 0, 0);
  };

  // Q B-frags: col=q=(l&31), k-dim=d=(l>>5)*8 + dd*16 + j
  bf16x8 qf[4];
  {
    const u16* qp = qkv + base + (size_t)(q0 + (l & 31)) * QKVC + (l >> 5) * 8;
    #pragma unroll
    for (int dd = 0; dd < 4; ++dd) qf[dd] = *(const bf16x8*)(qp + dd*16);
  }

  f32x16 o0{}, o1{};              // O[q=row(r)][d=(l&31)+{0,32}]
  float m = -1e30f, lsum = 0.f;   // per-lane (q = l&31, own k-rows)

  // prologue ledger: K0, V0, K1 (6 ops outstanding; qf loads ahead of them)
  stageK(kb, 0);
  stageV(kb, 0);
  stageK(kb + (U > 1 ? 1 : 0), 1);

  const u32 vbytes = lds_off(Vreg) + (l & 15)*8 + ((l >> 4) & 1)*128 + (l >> 5)*1024;

  int cb3 = 0;                    // it % 3 (K buffer)
  int vb2 = 0;                    // it % 2 (V buffer)
  for (int it = 0; it < U; ++it){
    const int u = kb + it;

    // own K(it)+V(it) landed (K(it+1) stays in flight); then align waves, NO drain
    asm volatile("s_waitcnt vmcnt(2)" ::: "memory");
    __builtin_amdgcn_sched_barrier(0);
    __builtin_amdgcn_s_barrier();
    __builtin_amdgcn_sched_barrier(0);

    // V before K (keeps the two unwaited ops == next-K); clamp at tail
    stageV(u + 1 > kmax ? kmax : u + 1, vb2 ^ 1);
    stageK(u + 2 > kmax ? kmax : u + 2, cb3 == 0 ? 2 : cb3 - 1);

    // ---- QK^T: S^T[k 0..31][q], 4 MFMA
    f32x16 a0{};
    const int r0 = l & 31;
    #pragma unroll
    for (int dd = 0; dd < 4; ++dd){
      const int c = dd*2 + (l >> 5);
      const bf16x8 k0 = *(const bf16x8*)&Kreg[cb3*2048 + r0*64 + ((c ^ (r0 & 7)))*8];
      a0 = MFMA32(k0, qf[dd], a0);
    }

    // ---- causal mask (units reaching past the wave's first q-row)
    if (u*32 + 31 > q0){
      const int qg = q0 + (l & 31);
      #pragma unroll
      for (int r = 0; r < 16; ++r){
        const int kg = u*32 + (r & 3) + 8*(r >> 2) + 4*(l >> 5);
        if (kg > qg) a0[r] = -1e30f;
      }
    }

    // ---- row-max
    float pm = -1e30f;
    #pragma unroll
    for (int r = 0; r < 16; ++r) pm = fmaxf(pm, a0[r]);
    pm = fmaxf(pm, __shfl(pm, l ^ 32));

    // ---- issue all 8 tr_reads; softmax below hides LDS latency
    s16x4 tr[8];
    {
      const u32 vb = vbytes + (u32)vb2 * 4096u;
      #pragma unroll
      for (int kk = 0; kk < 2; ++kk){
        asm volatile("ds_read_b64_tr_b16 %0, %4 offset:0\n\t"
                     "ds_read_b64_tr_b16 %1, %4 offset:512\n\t"
                     "ds_read_b64_tr_b16 %2, %4 offset:256\n\t"
                     "ds_read_b64_tr_b16 %3, %4 offset:768"
                     : "=&v"(tr[kk*4+0]), "=&v"(tr[kk*4+1]),
                       "=&v"(tr[kk*4+2]), "=&v"(tr[kk*4+3])
                     : "v"(vb + kk*2048));
      }
    }

    if (__any(pm > m + 64.f)){            // T13 defer-max
      const float mn = fmaxf(m, pm);
      const float corr = exp2f((m - mn) * CEXP);
      m = mn;
      lsum *= corr;
      #pragma unroll
      for (int r = 0; r < 16; ++r){
        const int row = (r & 3) + 8*(r >> 2) + 4*(l >> 5);
        const float cr = __shfl(corr, row | (l & 32));
        o0[r] *= cr; o1[r] *= cr;
      }
    }
    #pragma unroll
    for (int r = 0; r < 16; ++r){
      const float p = exp2f((a0[r] - m) * CEXP);
      lsum += p;
      a0[r] = p;
    }

    // ---- wait V once, then PV: A-frag via cvt_pk + permlane32_swap
    asm volatile("s_waitcnt lgkmcnt(0)" ::: "memory");
    __builtin_amdgcn_sched_barrier(0);
    #pragma unroll
    for (int kk = 0; kk < 2; ++kk){
      const int o = kk * 8;
      const u32 x0 = pk2(a0[o+0], a0[o+1]);
      const u32 x1 = pk2(a0[o+2], a0[o+3]);
      const u32 y0 = pk2(a0[o+4], a0[o+5]);
      const u32 y1 = pk2(a0[o+6], a0[o+7]);
      const u32x2 r0v = __builtin_amdgcn_permlane32_swap(x0, y0, false, false);
      const u32x2 r1v = __builtin_amdgcn_permlane32_swap(x1, y1, false, false);
      union { u32 wd[4]; bf16x8 v; } af;
      af.wd[0] = r0v[0]; af.wd[1] = r1v[0]; af.wd[2] = r0v[1]; af.wd[3] = r1v[1];
      union { s16x4 hh[2]; bf16x8 v; } b0, b1;
      b0.hh[0] = tr[kk*4+0]; b0.hh[1] = tr[kk*4+1];
      b1.hh[0] = tr[kk*4+2]; b1.hh[1] = tr[kk*4+3];
      o0 = MFMA32(af.v, b0.v, o0);
      o1 = MFMA32(af.v, b1.v, o1);
    }

    cb3 = (cb3 == 2) ? 0 : cb3 + 1;
    vb2 ^= 1;
  }

  // ---- cross-half merge (once): __syncthreads drains all DMA before LDS reuse
  lsum += __shfl(lsum, l ^ 32);             // combine lane k-halves (same q)
  __syncthreads();
  float* const Osh  = (float*)smem;                         // 16 KB
  float2* const MLsh = (float2*)((char*)smem + 16384);      // 1 KB

  if (hr == 1){
    #pragma unroll
    for (int r = 0; r < 16; ++r){
      Osh[wr*2048 + l*32 + r]      = o0[r];
      Osh[wr*2048 + l*32 + 16 + r] = o1[r];
    }
    MLsh[wr*64 + l] = float2{m, lsum};
  }
  __syncthreads();

  if (hr == 0){
    const float2 ml1 = MLsh[wr*64 + l];
    const float mm = fmaxf(m, ml1.x);
    const float c0 = exp2f((m - mm) * CEXP);
    const float c1 = exp2f((ml1.x - mm) * CEXP);
    const float lm = lsum*c0 + ml1.y*c1;    // >0 always (half-0 non-empty)
    const float a0q = c0 / lm;
    const float a1q = c1 / lm;
    #pragma unroll
    for (int r = 0; r < 16; ++r){
      const int row = (r & 3) + 8*(r >> 2) + 4*(l >> 5);
      const float f0 = __shfl(a0q, row | (l & 32));
      const float f1 = __shfl(a1q, row | (l & 32));
      const int qg = q0 + row;
      u16* op = aout + (size_t)(b*SEQ + qg) * HIDDEN + h*64 + (l & 31);
      op[0]  = f2bf(o0[r]*f0 + Osh[wr*2048 + l*32 + r]*f1);
      op[32] = f2bf(o1[r]*f0 + Osh[wr*2048 + l*32 + 16 + r]*f1);
    }
  }
}

// ---------------- launch ----------------
extern "C" void kernel_launch(void* const* d_in, const int* in_sizes, int n_in,
                              void* d_out, int out_size, void* d_ws, size_t ws_size,
                              hipStream_t stream){
  const float* enc    = (const float*)d_in[0];
  const float* attn_w = (const float*)d_in[1];
  const float* attn_b = (const float*)d_in[2];
  const float* out_w  = (const float*)d_in[3];
  const float* out_b  = (const float*)d_in[4];

  char* ws = (char*)d_ws;
  u16* aout   = (u16*)(ws);                          // attn output bf16 (8 MB slot)
  u16* wa_bf  = (u16*)(ws + (size_t)( 8u << 20));
  u16* wo_bf  = (u16*)(ws + (size_t)(14u << 20));
  u16* qkv    = (u16*)(ws + (size_t)(16u << 20));

  k_cvt2<<<dim3((CVT_N1+CVT_N2 + 255)/256), 256, 0, stream>>>(attn_w, out_w, wa_bf, wo_bf);

  k_gemmA32<<<dim3(MROWS/128, QKVC/128), 256, 0, stream>>>(enc, wa_bf, attn_b, qkv);
  k_attn<<<dim3(32, 32), 256, 0, stream>>>(qkv, aout);
  k_gemm<HIDDEN, false><<<dim3(MROWS/128, HIDDEN/128), 256, 0, stream>>>(aout, wo_bf, out_b, d_out);
}

// Round 22
// 105.108 us; speedup vs baseline: 1.0101x; 1.0101x over previous
//
#include <hip/hip_runtime.h>
#include <hip/hip_bf16.h>
#include <stdint.h>

#define HIDDEN 1024
#define NHEADS 16
#define DHEAD  64
#define BATCH  2
#define SEQ    2048
#define MROWS  (BATCH*SEQ)   // 4096
#define QKVC   (3*HIDDEN)    // 3072

typedef unsigned short u16;
typedef unsigned int   u32;
typedef __bf16 bf16x8 __attribute__((ext_vector_type(8)));
typedef __bf16 bf16x2 __attribute__((ext_vector_type(2)));
typedef float  f32x4  __attribute__((ext_vector_type(4)));
typedef float  f32x16 __attribute__((ext_vector_type(16)));
typedef short  s16x4  __attribute__((ext_vector_type(4)));
typedef u16    u16x8  __attribute__((ext_vector_type(8)));
typedef u32    u32x2  __attribute__((ext_vector_type(2)));

typedef const __attribute__((address_space(1))) void gvoid_t;
typedef       __attribute__((address_space(3))) void lvoid_t;

__device__ __forceinline__ gvoid_t* to_glob(const void* p){
  return (gvoid_t*)(uintptr_t)p;
}
__device__ __forceinline__ lvoid_t* to_lds(void* p){
  return (lvoid_t*)(uintptr_t)p;
}
__device__ __forceinline__ u32 lds_off(const void* p){
  return (u32)(uintptr_t)p;
}

// native f32->bf16 (hardware RNE cvt on gfx950)
__device__ __forceinline__ u16 f2bf(float x){
  __bf16 h = (__bf16)x;
  return __builtin_bit_cast(u16, h);
}
// packed f32x2 -> bf16x2 word (compiler emits v_cvt_pk_bf16_f32)
__device__ __forceinline__ u32 pk2(float a, float b){
  bf16x2 t = { (__bf16)a, (__bf16)b };
  return __builtin_bit_cast(u32, t);
}

#define MFMA32(a, b, c) __builtin_amdgcn_mfma_f32_32x32x16_bf16(a, b, c, 0, 0, 0)

// ---------------- fp32 -> bf16 conversion, all 3 inputs in one launch ----------------
// (R21's cvt-into-gemm fusion reverted: writeA ds_writes cost gemm1 more than
// the cvt saving — measured 104.7 -> 106.2.)
#define CVT_N0 1048576   // enc      (4M f32 / 4)
#define CVT_N1  786432   // attn_w   (3M f32 / 4)
#define CVT_N2  262144   // out_w    (1M f32 / 4)
__global__ __launch_bounds__(256) void k_cvt3(const float* __restrict__ e,
                                              const float* __restrict__ wa,
                                              const float* __restrict__ wo,
                                              u16* __restrict__ eb,
                                              u16* __restrict__ wab,
                                              u16* __restrict__ wob){
  int i = blockIdx.x * 256 + threadIdx.x;
  const float* src; u16* dst;
  if (i < CVT_N0){ src = e; dst = eb; }
  else if (i < CVT_N0 + CVT_N1){ i -= CVT_N0; src = wa; dst = wab; }
  else if (i < CVT_N0 + CVT_N1 + CVT_N2){ i -= CVT_N0 + CVT_N1; src = wo; dst = wob; }
  else return;
  const float4 v = reinterpret_cast<const float4*>(src)[i];
  ushort4 o;
  o.x = f2bf(v.x); o.y = f2bf(v.y); o.z = f2bf(v.z); o.w = f2bf(v.w);
  reinterpret_cast<ushort4*>(dst)[i] = o;
}

// ---------------- bf16 GEMM, C = A * B^T + bias (R20-verified: T2 swizzle) ----------------
template<int NC, bool BF16OUT>
__global__ __launch_bounds__(256) void k_gemm(const u16* __restrict__ A,
                                              const u16* __restrict__ B,
                                              const float* __restrict__ bias,
                                              void* __restrict__ C){
  constexpr int K = HIDDEN;
  __shared__ u16 As[2][128*32];
  __shared__ u16 Bs[2][128*32];
  const int m0 = blockIdx.x * 128;
  const int n0 = blockIdx.y * 128;
  const int tid = threadIdx.x;
  const int w = tid >> 6, l = tid & 63;
  const int wr = w >> 1, wc = w & 1;

  const f32x4 fz = {0.f, 0.f, 0.f, 0.f};
  f32x4 acc[4][4];
  #pragma unroll
  for (int i = 0; i < 4; ++i)
    #pragma unroll
    for (int j = 0; j < 4; ++j) acc[i][j] = fz;

  const int sc = (tid & 3) ^ (((tid >> 2) >> 1) & 3);
  const u16* ap = A + (size_t)(m0 + (tid >> 2)) * K + sc * 8;
  const u16* bp = B + (size_t)(n0 + (tid >> 2)) * K + sc * 8;

  auto stage = [&](int k0, int buf){
    __builtin_amdgcn_global_load_lds(to_glob(ap + k0),        to_lds(&As[buf][w*512]),        16, 0, 0);
    __builtin_amdgcn_global_load_lds(to_glob(ap + 64*K + k0), to_lds(&As[buf][2048 + w*512]), 16, 0, 0);
    __builtin_amdgcn_global_load_lds(to_glob(bp + k0),        to_lds(&Bs[buf][w*512]),        16, 0, 0);
    __builtin_amdgcn_global_load_lds(to_glob(bp + 64*K + k0), to_lds(&Bs[buf][2048 + w*512]), 16, 0, 0);
  };

  stage(0, 0);
  __syncthreads();

  const int chunkSel = ((l >> 4) ^ ((l >> 1) & 3)) * 8;   // swizzled read chunk

  for (int k0 = 0; k0 < K; k0 += 32){
    const int cur = (k0 >> 5) & 1;
    if (k0 + 32 < K) stage(k0 + 32, cur ^ 1);

    bf16x8 af[4], bfr[4];
    #pragma unroll
    for (int mf = 0; mf < 4; ++mf)
      af[mf]  = *(const bf16x8*)&As[cur][(wr*64 + mf*16 + (l & 15))*32 + chunkSel];
    #pragma unroll
    for (int nf = 0; nf < 4; ++nf)
      bfr[nf] = *(const bf16x8*)&Bs[cur][(wc*64 + nf*16 + (l & 15))*32 + chunkSel];
    #pragma unroll
    for (int mf = 0; mf < 4; ++mf)
      #pragma unroll
      for (int nf = 0; nf < 4; ++nf)
        acc[mf][nf] = __builtin_amdgcn_mfma_f32_16x16x32_bf16(af[mf], bfr[nf], acc[mf][nf], 0, 0, 0);

    __syncthreads();
  }

  #pragma unroll
  for (int nf = 0; nf < 4; ++nf){
    const int col = n0 + wc*64 + nf*16 + (l & 15);
    const float bv = bias[col];
    #pragma unroll
    for (int mf = 0; mf < 4; ++mf){
      #pragma unroll
      for (int r = 0; r < 4; ++r){
        const int row = m0 + wr*64 + mf*16 + (l >> 4)*4 + r;
        const float v = acc[mf][nf][r] + bv;
        if constexpr (BF16OUT) ((u16*)C)[(size_t)row * NC + col] = f2bf(v);
        else                   ((float*)C)[(size_t)row * NC + col] = v;
      }
    }
  }
}

// ---------------- causal flash attention: counted-vmcnt, K 3-buf / V 2-buf ----
// R12/R19/R20 engine (verified 45.8-46.6us / absmax 0.0049), R22 change:
// BALANCED qt remap. CU c hosts linear blocks {c, c+256, c+512, c+768} ->
// y in {y0, y0+8, y0+16, y0+24}. Old map (31-y) gave per-CU work sums
// 48..76 units (37% spread -> makespan set by 76-unit CUs). New stratified
// map (quarters 0..7 / 31..24 / 8..15 / 23..16) makes EVERY such quadruple
// sum to exactly 62. Bijective; dispatch-mapping is a perf heuristic only.
// Known dead ends (R13-R18): sync-scheme changes plateau-neutral; tail
// equalization spills; permlane32_swap(x,x) self-swap BANNED.
__global__ __launch_bounds__(256, 4) void k_attn(const u16* __restrict__ qkv,
                                                 u16* __restrict__ aout){
  __shared__ u16 smem[20480];   // 40 KiB: half hr at [hr*10240]: K 3x2048 | V 2x2048 (u16)

  const int bh = blockIdx.x;
  const int b  = bh >> 4;
  const int h  = bh & 15;
  const int yy = blockIdx.y;
  const int yq = yy & 7;
  int qt;                                   // balanced stratified map
  switch (yy >> 3){
    case 0:  qt = yq;      break;           // 0..7
    case 1:  qt = 31 - yq; break;           // 31..24
    case 2:  qt = 8 + yq;  break;           // 8..15
    default: qt = 23 - yq; break;           // 23..16
  }
  const int tid = threadIdx.x;
  const int l  = tid & 63;
  const int w  = tid >> 6;
  const int hr = w >> 1;                   // k-half (0 or 1)
  const int wr = w & 1;                    // q-row half within tile
  const int t128 = tid & 127;
  const int lw = t128 >> 6;                // wave-within-half
  const int U  = qt + 1;                   // 32-k units per half (uniform)
  const int kb = hr ? U : 0;               // my first unit
  const int kmax = kb + U - 1;             // clamp target for tail prefetch
  const int q0 = qt*64 + wr*32;            // this wave's 32 q-rows
  const size_t base = (size_t)b * SEQ * QKVC + (size_t)h * 192;
  const float CEXP = 0.18033688011112042f; // 0.125 * log2(e)

  u16* const Kreg = smem + hr*10240;          // + cb*2048 (u16), cb in {0,1,2}
  u16* const Vreg = smem + hr*10240 + 6144;   // + vb*2048 (u16), vb in {0,1}

  // ---- per-lane staging source bases (XOR pre-swizzled K; inverse-subtile V)
  const int cgK = (t128 & 7) ^ ((t128 >> 3) & 7);
  const u16* const baseK = qkv + base + (size_t)(t128 >> 3) * QKVC + 64 + cgK * 8;
  const int vk = ((t128 >> 5) << 2) | ((t128 >> 1) & 3);
  const int vd = (((t128 >> 3) & 3) << 4) | ((t128 & 1) << 3);
  const u16* const baseV = qkv + base + (size_t)vk * QKVC + 128 + vd;

  auto stageK = [&](int u, int cb){   // 2 vmem instrs per wave
    const u16* pk = baseK + (size_t)u * 32 * QKVC;
    #pragma unroll
    for (int t = 0; t < 2; ++t)
      __builtin_amdgcn_global_load_lds(to_glob(pk + t*16*QKVC),
                                       to_lds(&Kreg[cb*2048 + t*1024 + lw*512]), 16, 0, 0);
  };
  auto stageV = [&](int u, int vb){   // 2 vmem instrs per wave
    const u16* pv = baseV + (size_t)u * 32 * QKVC;
    #pragma unroll
    for (int t = 0; t < 2; ++t)
      __builtin_amdgcn_global_load_lds(to_glob(pv + t*16*QKVC),
                                       to_lds(&Vreg[vb*2048 + t*1024 + lw*512]), 16, 0, 0);
  };

  // Q B-frags: col=q=(l&31), k-dim=d=(l>>5)*8 + dd*16 + j
  bf16x8 qf[4];
  {
    const u16* qp = qkv + base + (size_t)(q0 + (l & 31)) * QKVC + (l >> 5) * 8;
    #pragma unroll
    for (int dd = 0; dd < 4; ++dd) qf[dd] = *(const bf16x8*)(qp + dd*16);
  }

  f32x16 o0{}, o1{};              // O[q=row(r)][d=(l&31)+{0,32}]
  float m = -1e30f, lsum = 0.f;   // per-lane (q = l&31, own k-rows)

  // prologue ledger: K0, V0, K1 (6 ops outstanding; qf loads ahead of them)
  stageK(kb, 0);
  stageV(kb, 0);
  stageK(kb + (U > 1 ? 1 : 0), 1);

  const u32 vbytes = lds_off(Vreg) + (l & 15)*8 + ((l >> 4) & 1)*128 + (l >> 5)*1024;

  int cb3 = 0;                    // it % 3 (K buffer)
  int vb2 = 0;                    // it % 2 (V buffer)
  for (int it = 0; it < U; ++it){
    const int u = kb + it;

    // own K(it)+V(it) landed (K(it+1) stays in flight); then align waves, NO drain
    asm volatile("s_waitcnt vmcnt(2)" ::: "memory");
    __builtin_amdgcn_sched_barrier(0);
    __builtin_amdgcn_s_barrier();
    __builtin_amdgcn_sched_barrier(0);

    // V before K (keeps the two unwaited ops == next-K); clamp at tail
    stageV(u + 1 > kmax ? kmax : u + 1, vb2 ^ 1);
    stageK(u + 2 > kmax ? kmax : u + 2, cb3 == 0 ? 2 : cb3 - 1);

    // ---- QK^T: S^T[k 0..31][q], 4 MFMA
    f32x16 a0{};
    const int r0 = l & 31;
    #pragma unroll
    for (int dd = 0; dd < 4; ++dd){
      const int c = dd*2 + (l >> 5);
      const bf16x8 k0 = *(const bf16x8*)&Kreg[cb3*2048 + r0*64 + ((c ^ (r0 & 7)))*8];
      a0 = MFMA32(k0, qf[dd], a0);
    }

    // ---- causal mask (units reaching past the wave's first q-row)
    if (u*32 + 31 > q0){
      const int qg = q0 + (l & 31);
      #pragma unroll
      for (int r = 0; r < 16; ++r){
        const int kg = u*32 + (r & 3) + 8*(r >> 2) + 4*(l >> 5);
        if (kg > qg) a0[r] = -1e30f;
      }
    }

    // ---- row-max
    float pm = -1e30f;
    #pragma unroll
    for (int r = 0; r < 16; ++r) pm = fmaxf(pm, a0[r]);
    pm = fmaxf(pm, __shfl(pm, l ^ 32));

    // ---- issue all 8 tr_reads; softmax below hides LDS latency
    s16x4 tr[8];
    {
      const u32 vb = vbytes + (u32)vb2 * 4096u;
      #pragma unroll
      for (int kk = 0; kk < 2; ++kk){
        asm volatile("ds_read_b64_tr_b16 %0, %4 offset:0\n\t"
                     "ds_read_b64_tr_b16 %1, %4 offset:512\n\t"
                     "ds_read_b64_tr_b16 %2, %4 offset:256\n\t"
                     "ds_read_b64_tr_b16 %3, %4 offset:768"
                     : "=&v"(tr[kk*4+0]), "=&v"(tr[kk*4+1]),
                       "=&v"(tr[kk*4+2]), "=&v"(tr[kk*4+3])
                     : "v"(vb + kk*2048));
      }
    }

    if (__any(pm > m + 64.f)){            // T13 defer-max
      const float mn = fmaxf(m, pm);
      const float corr = exp2f((m - mn) * CEXP);
      m = mn;
      lsum *= corr;
      #pragma unroll
      for (int r = 0; r < 16; ++r){
        const int row = (r & 3) + 8*(r >> 2) + 4*(l >> 5);
        const float cr = __shfl(corr, row | (l & 32));
        o0[r] *= cr; o1[r] *= cr;
      }
    }
    #pragma unroll
    for (int r = 0; r < 16; ++r){
      const float p = exp2f((a0[r] - m) * CEXP);
      lsum += p;
      a0[r] = p;
    }

    // ---- wait V once, then PV: A-frag via cvt_pk + permlane32_swap
    asm volatile("s_waitcnt lgkmcnt(0)" ::: "memory");
    __builtin_amdgcn_sched_barrier(0);
    #pragma unroll
    for (int kk = 0; kk < 2; ++kk){
      const int o = kk * 8;
      const u32 x0 = pk2(a0[o+0], a0[o+1]);
      const u32 x1 = pk2(a0[o+2], a0[o+3]);
      const u32 y0 = pk2(a0[o+4], a0[o+5]);
      const u32 y1 = pk2(a0[o+6], a0[o+7]);
      const u32x2 r0v = __builtin_amdgcn_permlane32_swap(x0, y0, false, false);
      const u32x2 r1v = __builtin_amdgcn_permlane32_swap(x1, y1, false, false);
      union { u32 wd[4]; bf16x8 v; } af;
      af.wd[0] = r0v[0]; af.wd[1] = r1v[0]; af.wd[2] = r0v[1]; af.wd[3] = r1v[1];
      union { s16x4 hh[2]; bf16x8 v; } b0, b1;
      b0.hh[0] = tr[kk*4+0]; b0.hh[1] = tr[kk*4+1];
      b1.hh[0] = tr[kk*4+2]; b1.hh[1] = tr[kk*4+3];
      o0 = MFMA32(af.v, b0.v, o0);
      o1 = MFMA32(af.v, b1.v, o1);
    }

    cb3 = (cb3 == 2) ? 0 : cb3 + 1;
    vb2 ^= 1;
  }

  // ---- cross-half merge (once): __syncthreads drains all DMA before LDS reuse
  lsum += __shfl(lsum, l ^ 32);             // combine lane k-halves (same q)
  __syncthreads();
  float* const Osh  = (float*)smem;                         // 16 KB
  float2* const MLsh = (float2*)((char*)smem + 16384);      // 1 KB

  if (hr == 1){
    #pragma unroll
    for (int r = 0; r < 16; ++r){
      Osh[wr*2048 + l*32 + r]      = o0[r];
      Osh[wr*2048 + l*32 + 16 + r] = o1[r];
    }
    MLsh[wr*64 + l] = float2{m, lsum};
  }
  __syncthreads();

  if (hr == 0){
    const float2 ml1 = MLsh[wr*64 + l];
    const float mm = fmaxf(m, ml1.x);
    const float c0 = exp2f((m - mm) * CEXP);
    const float c1 = exp2f((ml1.x - mm) * CEXP);
    const float lm = lsum*c0 + ml1.y*c1;    // >0 always (half-0 non-empty)
    const float a0q = c0 / lm;
    const float a1q = c1 / lm;
    #pragma unroll
    for (int r = 0; r < 16; ++r){
      const int row = (r & 3) + 8*(r >> 2) + 4*(l >> 5);
      const float f0 = __shfl(a0q, row | (l & 32));
      const float f1 = __shfl(a1q, row | (l & 32));
      const int qg = q0 + row;
      u16* op = aout + (size_t)(b*SEQ + qg) * HIDDEN + h*64 + (l & 31);
      op[0]  = f2bf(o0[r]*f0 + Osh[wr*2048 + l*32 + r]*f1);
      op[32] = f2bf(o1[r]*f0 + Osh[wr*2048 + l*32 + 16 + r]*f1);
    }
  }
}

// ---------------- launch ----------------
extern "C" void kernel_launch(void* const* d_in, const int* in_sizes, int n_in,
                              void* d_out, int out_size, void* d_ws, size_t ws_size,
                              hipStream_t stream){
  const float* enc    = (const float*)d_in[0];
  const float* attn_w = (const float*)d_in[1];
  const float* attn_b = (const float*)d_in[2];
  const float* out_w  = (const float*)d_in[3];
  const float* out_b  = (const float*)d_in[4];

  char* ws = (char*)d_ws;
  u16* enc_bf = (u16*)(ws);
  u16* wa_bf  = (u16*)(ws + (size_t)( 8u << 20));
  u16* wo_bf  = (u16*)(ws + (size_t)(14u << 20));
  u16* qkv    = (u16*)(ws + (size_t)(16u << 20));
  u16* aout   = enc_bf;  // safe alias: attn runs strictly after GEMM1

  k_cvt3<<<dim3((CVT_N0+CVT_N1+CVT_N2 + 255)/256), 256, 0, stream>>>(
      enc, attn_w, out_w, enc_bf, wa_bf, wo_bf);

  k_gemm<QKVC,  true ><<<dim3(MROWS/128, QKVC/128),  256, 0, stream>>>(enc_bf, wa_bf, attn_b, qkv);
  k_attn<<<dim3(32, 32), 256, 0, stream>>>(qkv, aout);
  k_gemm<HIDDEN, false><<<dim3(MROWS/128, HIDDEN/128), 256, 0, stream>>>(aout, wo_bf, out_b, d_out);
}